// Round 5
// baseline (434.791 us; speedup 1.0000x reference)
//
#include <hip/hip_runtime.h>
#include <hip/hip_bf16.h>

// LRU forward, bf16-MFMA pipeline, round 5.
//  drive = gamma*(X@B^T)+bias_h (complex); h_t = lam*h_{t-1}+d_t;
//  Y = Re(H@C^T) + X@D^T + bias_out.
// Round-5 changes (fused2 was latency-bound: occ 21%, 2.6M LDS conflicts):
//  * LCH 64->32: 2048 fused2 blocks, Hs 64KB->32KB -> 5 blocks/CU.
//  * re/im interleaved in Hbuf rows and Ccat K-order: scan = 1 u32 load +
//    1 u32 LDS write per step (was 2+2 u16; same-dword write conflicts gone).
// Layouts:
//  Hbuf row (1024 u16): [re0,im0,re1,im1,...] (channel c at u16 2c/2c+1)
//  Ccat [256][1280]: k<1024: k=2c -> Cre[:,c], k=2c+1 -> -Cim[:,c]; k>=1024: D
//  Bcat [1024][256]: rows 0-511 Bre, 512-1023 Bim (gemm1 N-dim, unchanged)

#define TT     4096
#define BATCHN 16
#define MM     (BATCHN * TT)
#define LCH    32
#define NCH    (TT / LCH)   // 128

typedef unsigned short u16;
typedef unsigned int u32;
typedef short bf16x8 __attribute__((ext_vector_type(8)));
typedef float f32x4 __attribute__((ext_vector_type(4)));

__device__ __forceinline__ u16 f2bf(float f) {
  union { __hip_bfloat16 b; u16 u; } cv;
  cv.b = __float2bfloat16(f);
  return cv.u;
}
__device__ __forceinline__ float bf2f(u16 u) {
  union { u16 u; __hip_bfloat16 b; } cv;
  cv.u = u;
  return __bfloat162float(cv.b);
}

// ---------------- params ----------------
__global__ void k_params(const float* __restrict__ nu_log,
                         const float* __restrict__ theta_log,
                         float* __restrict__ P) {
  int h = threadIdx.x;
  if (h >= 512) return;
  double nu  = exp((double)nu_log[h]);
  double th  = exp((double)theta_log[h]);
  double mag = exp(-nu);
  double g   = sqrt(fmax(0.0, 1.0 - mag * mag));
  double magL = exp(-(double)LCH * nu);
  double aL   = (double)LCH * th;
  P[h]        = (float)(mag * cos(th));   // lam_re
  P[512 + h]  = (float)(mag * sin(th));   // lam_im
  P[1024 + h] = (float)g;                 // gamma
  P[1536 + h] = (float)(magL * cos(aL));  // lam^L re
  P[2048 + h] = (float)(magL * sin(aL));  // lam^L im
}

// ---------------- weight prep ----------------
__global__ void k_prep_w(const float* __restrict__ Bre, const float* __restrict__ Bim,
                         const float* __restrict__ Cre, const float* __restrict__ Cim,
                         const float* __restrict__ D, u16* __restrict__ Bcat,
                         u16* __restrict__ Ccat) {
  const int NB = 1024 * 256;
  const int NC = 256 * 1280;
  for (int idx = blockIdx.x * blockDim.x + threadIdx.x; idx < NB + NC;
       idx += gridDim.x * blockDim.x) {
    if (idx < NB) {
      int row = idx >> 8, col = idx & 255;
      float v = (row < 512) ? Bre[row * 256 + col] : Bim[(row - 512) * 256 + col];
      Bcat[idx] = f2bf(v);
    } else {
      int j = idx - NB;
      int o = j / 1280, k = j % 1280;
      float v;
      if (k < 1024) {
        int ch = k >> 1;
        v = (k & 1) ? -Cim[o * 512 + ch] : Cre[o * 512 + ch];
      } else {
        v = D[o * 256 + (k - 1024)];
      }
      Ccat[j] = f2bf(v);
    }
  }
}

// ---------------- X -> bf16 ----------------
__global__ __launch_bounds__(256) void k_prep_x(const float* __restrict__ X,
                                                u16* __restrict__ Xb) {
  int idx = blockIdx.x * 256 + threadIdx.x;
  const float4* s = (const float4*)X + (size_t)idx * 2;
  float4 a = s[0], b = s[1];
  u16 o[8] = {f2bf(a.x), f2bf(a.y), f2bf(a.z), f2bf(a.w),
              f2bf(b.x), f2bf(b.y), f2bf(b.z), f2bf(b.w)};
  *(int4*)(Xb + (size_t)idx * 8) = *(const int4*)o;
}

// ---------------- GEMM1: Hbuf(drive, interleaved) = epi(Xb @ Bcat^T) --------
__global__ __launch_bounds__(256) void k_gemm1(
    const u16* __restrict__ Xb, const u16* __restrict__ Bcat,
    const float* __restrict__ P, const float* __restrict__ bhr,
    const float* __restrict__ bhi, u16* __restrict__ Hbuf) {
  __shared__ __align__(16) char smem[2 * 128 * 64 * 2];
  char* sA = smem;
  char* sB = smem + 128 * 64 * 2;
  const int tid = threadIdx.x;
  const int lane = tid & 63;
  const int wid = tid >> 6;
  const int wr = wid >> 1, wc = wid & 1;
  const int mb = blockIdx.x * 128;
  const int nb = blockIdx.y * 128;

  f32x4 acc[4][4];
#pragma unroll
  for (int r = 0; r < 4; ++r)
#pragma unroll
    for (int c = 0; c < 4; ++c) acc[r][c] = (f32x4)0.f;

  for (int kt = 0; kt < 4; ++kt) {
    const int k0 = kt * 64;
    __syncthreads();
#pragma unroll
    for (int i = 0; i < 4; ++i) {
      int s = i * 256 + tid;
      int row = s >> 3, slot = s & 7;
      int4 va = *(const int4*)(Xb + (size_t)(mb + row) * 256 + k0 + slot * 8);
      int4 vb = *(const int4*)(Bcat + (size_t)(nb + row) * 256 + k0 + slot * 8);
      int soff = row * 128 + ((slot ^ (row & 7)) << 4);
      *(int4*)(sA + soff) = va;
      *(int4*)(sB + soff) = vb;
    }
    __syncthreads();
#pragma unroll
    for (int kk = 0; kk < 2; ++kk) {
      bf16x8 af[4], bfr[4];
#pragma unroll
      for (int r = 0; r < 4; ++r) {
        int row = wr * 64 + r * 16 + (lane & 15);
        int slot = (kk * 4 + (lane >> 4)) ^ (row & 7);
        af[r] = *(const bf16x8*)(sA + row * 128 + slot * 16);
      }
#pragma unroll
      for (int c = 0; c < 4; ++c) {
        int row = wc * 64 + c * 16 + (lane & 15);
        int slot = (kk * 4 + (lane >> 4)) ^ (row & 7);
        bfr[c] = *(const bf16x8*)(sB + row * 128 + slot * 16);
      }
#pragma unroll
      for (int r = 0; r < 4; ++r)
#pragma unroll
        for (int c = 0; c < 4; ++c)
          acc[r][c] = __builtin_amdgcn_mfma_f32_16x16x32_bf16(af[r], bfr[c],
                                                              acc[r][c], 0, 0, 0);
    }
  }
  const int rbase = (lane >> 4) * 4;
  const int cbase = lane & 15;
#pragma unroll
  for (int r = 0; r < 4; ++r)
#pragma unroll
    for (int c = 0; c < 4; ++c) {
      int col = nb + wc * 64 + c * 16 + cbase;
      int h = col & 511;
      float g = P[1024 + h];
      float bias = (col < 512) ? bhr[h] : bhi[h];
      int icol = (col < 512) ? (2 * col) : (2 * (col - 512) + 1);
#pragma unroll
      for (int q = 0; q < 4; ++q) {
        int row = mb + wr * 64 + r * 16 + rbase + q;
        Hbuf[(size_t)row * 1024 + icol] = f2bf(fmaf(acc[r][c][q], g, bias));
      }
    }
}

// ---------------- scan pass F: chunk finals (interleaved u32 reads) ---------
__global__ __launch_bounds__(512) void k_scanF(
    const float* __restrict__ P, const u16* __restrict__ Hbuf,
    float* __restrict__ finr, float* __restrict__ fini) {
  const int h = threadIdx.x;
  const int b = blockIdx.x, c = blockIdx.y;
  const float lr = P[h], li = P[512 + h];
  float hr = 0.f, hi = 0.f;
  const u32* H32 = (const u32*)Hbuf;
  size_t base = ((size_t)b * TT + (size_t)c * LCH) * 512 + h;
#pragma unroll 8
  for (int j = 0; j < LCH; ++j) {
    u32 pk = H32[base];
    float dr = bf2f((u16)(pk & 0xffff));
    float di = bf2f((u16)(pk >> 16));
    float nr = fmaf(lr, hr, fmaf(-li, hi, dr));
    float ni = fmaf(lr, hi, fmaf(li, hr, di));
    hr = nr; hi = ni;
    base += 512;
  }
  size_t f = ((size_t)b * NCH + c) * 512 + h;
  finr[f] = hr; fini[f] = hi;
}

// ---------------- carry chain ----------------
__global__ __launch_bounds__(512) void k_carry(
    const float* __restrict__ P, const float* __restrict__ finr,
    const float* __restrict__ fini, float* __restrict__ carr,
    float* __restrict__ cari) {
  const int h = threadIdx.x;
  const int b = blockIdx.x;
  const float Lr = P[1536 + h], Li = P[2048 + h];
  float cr = 0.f, ci = 0.f;
  for (int c = 0; c < NCH; ++c) {
    size_t idx = ((size_t)b * NCH + c) * 512 + h;
    carr[idx] = cr; cari[idx] = ci;
    float fr = finr[idx], fi = fini[idx];
    float nr = fmaf(Lr, cr, fmaf(-Li, ci, fr));
    float ni = fmaf(Lr, ci, fmaf(Li, cr, fi));
    cr = nr; ci = ni;
  }
}

// ---------------- fused scan + output GEMM ----------------
// One block per (chunk c=32 steps, batch b). 256 threads = 4 waves.
// Phase q (q=0,1): scan channels q*256..q*256+255 (1 ch/thread, u32 loads,
// u32 LDS writes), then MFMA [32 x 256cols] vs Ccat K-half q.
// Tail: Xb tile [32][256] staged, MFMA vs D part. Hs = 32 KiB -> 5 blocks/CU.
__global__ __launch_bounds__(256) void k_fused2(
    const float* __restrict__ P, const u16* __restrict__ Hbuf,
    const u16* __restrict__ Xb, const u16* __restrict__ Ccat,
    const float* __restrict__ carr, const float* __restrict__ cari,
    const float* __restrict__ bo, float* __restrict__ Y) {
  __shared__ __align__(16) char Hs[32 * 1024];  // 32 KiB
  const int tid = threadIdx.x;
  const int lane = tid & 63;
  const int w = tid >> 6;            // wave = N-subtile (64 cols)
  const int c = blockIdx.x;
  const int b = blockIdx.y;
  const int row0 = b * TT + c * LCH;

  f32x4 acc[2][4];
#pragma unroll
  for (int m = 0; m < 2; ++m)
#pragma unroll
    for (int n = 0; n < 4; ++n) acc[m][n] = (f32x4)0.f;

  const u32* H32 = (const u32*)Hbuf;

#pragma unroll
  for (int q = 0; q < 2; ++q) {
    // ---- scan phase: channel ch = q*256 + tid ----
    const int ch = q * 256 + tid;
    const float lr = P[ch], li = P[512 + ch];
    size_t cidx = ((size_t)b * NCH + c) * 512 + ch;
    float hr = carr[cidx], hi = cari[cidx];
    size_t base = (size_t)row0 * 512 + ch;   // u32 index
    __syncthreads();  // previous MFMA phase done reading Hs
#pragma unroll 8
    for (int j = 0; j < LCH; ++j) {
      u32 pk = H32[base];
      float dr = bf2f((u16)(pk & 0xffff));
      float di = bf2f((u16)(pk >> 16));
      float nr = fmaf(lr, hr, fmaf(-li, hi, dr));
      float ni = fmaf(lr, hi, fmaf(li, hr, di));
      hr = nr; hi = ni;
      // logical 16B-slot t>>2 (4 u32/slot), swizzled by row j
      int soff = ((tid >> 2) ^ (j & 7)) * 16 + (tid & 3) * 4;
      *(u32*)(Hs + j * 1024 + soff) = (u32)f2bf(nr) | ((u32)f2bf(ni) << 16);
      base += 512;
    }
    __syncthreads();
    // ---- MFMA phase: K-half q (512 wide = 256 interleaved channels) ----
#pragma unroll 4
    for (int ks = 0; ks < 16; ++ks) {
      bf16x8 af[2], bfr[4];
#pragma unroll
      for (int m = 0; m < 2; ++m) {
        int row = m * 16 + (lane & 15);
        int slot = (ks * 4 + (lane >> 4)) ^ (row & 7);
        af[m] = *(const bf16x8*)(Hs + row * 1024 + slot * 16);
      }
#pragma unroll
      for (int n = 0; n < 4; ++n) {
        int col = w * 64 + n * 16 + (lane & 15);
        bfr[n] = *(const bf16x8*)(Ccat + (size_t)col * 1280 + q * 512 +
                                  ks * 32 + (lane >> 4) * 8);
      }
#pragma unroll
      for (int m = 0; m < 2; ++m)
#pragma unroll
        for (int n = 0; n < 4; ++n)
          acc[m][n] = __builtin_amdgcn_mfma_f32_16x16x32_bf16(af[m], bfr[n],
                                                              acc[m][n], 0, 0, 0);
    }
  }

  // ---- X tail: stage Xb [32][256] (pre-swizzled source), MFMA vs D ----
  __syncthreads();
#pragma unroll
  for (int i = 0; i < 4; ++i) {
    int p = i * 256 + tid;              // 16B unit, 32 slots/row
    int row = p >> 5, slot = p & 31;
    int4 v = *(const int4*)(Xb + (size_t)(row0 + row) * 256 +
                            ((slot ^ (row & 7)) * 8));
    *(int4*)(Hs + row * 512 + slot * 16) = v;
  }
  __syncthreads();
#pragma unroll 2
  for (int ks = 0; ks < 8; ++ks) {
    bf16x8 af[2], bfr[4];
#pragma unroll
    for (int m = 0; m < 2; ++m) {
      int row = m * 16 + (lane & 15);
      int slot = (ks * 4 + (lane >> 4)) ^ (row & 7);
      af[m] = *(const bf16x8*)(Hs + row * 512 + slot * 16);
    }
#pragma unroll
    for (int n = 0; n < 4; ++n) {
      int col = w * 64 + n * 16 + (lane & 15);
      bfr[n] = *(const bf16x8*)(Ccat + (size_t)col * 1280 + 1024 +
                                ks * 32 + (lane >> 4) * 8);
    }
#pragma unroll
    for (int m = 0; m < 2; ++m)
#pragma unroll
      for (int n = 0; n < 4; ++n)
        acc[m][n] = __builtin_amdgcn_mfma_f32_16x16x32_bf16(af[m], bfr[n],
                                                            acc[m][n], 0, 0, 0);
  }

  // ---- epilogue: Y = acc + bias ----
  const int rb = (lane >> 4) * 4;
  const int cb = lane & 15;
#pragma unroll
  for (int m = 0; m < 2; ++m)
#pragma unroll
    for (int n = 0; n < 4; ++n) {
      int col = w * 64 + n * 16 + cb;
      float bias = bo[col];
#pragma unroll
      for (int qq = 0; qq < 4; ++qq) {
        int row = row0 + m * 16 + rb + qq;
        Y[(size_t)row * 256 + col] = acc[m][n][qq] + bias;
      }
    }
}

extern "C" void kernel_launch(void* const* d_in, const int* in_sizes, int n_in,
                              void* d_out, int out_size, void* d_ws, size_t ws_size,
                              hipStream_t stream) {
  const float* X        = (const float*)d_in[0];
  const float* nu_log   = (const float*)d_in[1];
  const float* theta_lg = (const float*)d_in[2];
  const float* Bre      = (const float*)d_in[3];
  const float* Bim      = (const float*)d_in[4];
  const float* Cre      = (const float*)d_in[5];
  const float* Cim      = (const float*)d_in[6];
  const float* D        = (const float*)d_in[7];
  const float* bhr      = (const float*)d_in[8];
  const float* bhi      = (const float*)d_in[9];
  const float* bo       = (const float*)d_in[10];
  float* Y = (float*)d_out;
  char* ws = (char*)d_ws;

  size_t off = 0;
  float* P = (float*)(ws + off);            off += 2560 * 4;
  off = (off + 255) & ~(size_t)255;
  u16* Hbuf = (u16*)(ws + off);             off += (size_t)MM * 1024 * 2;  // 128 MiB
  u16* Xb   = (u16*)(ws + off);             off += (size_t)MM * 256 * 2;   // 32 MiB
  u16* Bcat = (u16*)(ws + off);             off += 1024 * 256 * 2;
  u16* Ccat = (u16*)(ws + off);             off += 256 * 1280 * 2;
  float* finr = (float*)(ws + off);         off += (size_t)BATCHN * NCH * 512 * 4;
  float* fini = (float*)(ws + off);         off += (size_t)BATCHN * NCH * 512 * 4;
  float* carr = (float*)(ws + off);         off += (size_t)BATCHN * NCH * 512 * 4;
  float* cari = (float*)(ws + off);         off += (size_t)BATCHN * NCH * 512 * 4;
  if (ws_size < off) return;

  k_params<<<1, 512, 0, stream>>>(nu_log, theta_lg, P);
  k_prep_w<<<512, 256, 0, stream>>>(Bre, Bim, Cre, Cim, D, Bcat, Ccat);
  k_prep_x<<<MM * 256 / (256 * 8), 256, 0, stream>>>(X, Xb);
  k_gemm1<<<dim3(MM / 128, 8), 256, 0, stream>>>(Xb, Bcat, P, bhr, bhi, Hbuf);
  k_scanF<<<dim3(BATCHN, NCH), 512, 0, stream>>>(P, Hbuf, finr, fini);
  k_carry<<<BATCHN, 512, 0, stream>>>(P, finr, fini, carr, cari);
  k_fused2<<<dim3(NCH, BATCHN), 256, 0, stream>>>(P, Hbuf, Xb, Ccat, carr, cari,
                                                  bo, Y);
}

// Round 7
// 332.211 us; speedup vs baseline: 1.3088x; 1.3088x over previous
//
#include <hip/hip_runtime.h>
#include <hip/hip_bf16.h>

// LRU forward, bf16-MFMA pipeline, round 7.
//  drive = gamma*(X@B^T)+bias_h (complex); h_t = lam*h_{t-1}+d_t;
//  Y = Re(H@C^T) + X@D^T + bias_out.
// r6 failed on (a) cross-block race in gemm1-fused finals (block wrote only
// re OR im half of a channel), (b) broken X-tail staging (half tile + slot
// aliasing). r7:
//  * Bcat rows re/im-INTERLEAVED -> gemm1 block owns both halves of its 64
//    channels; epilogue writes Hbuf col directly.
//  * chunk finals computed from an LDS mirror of the tile (no global re-read,
//    no race).
//  * X-tail restored to r4's verified 32-slot mapping (8 int4/thread).
//  * gemm1 staging via global_load_lds w=16 (pre-swizzled source, linear dest).
//  * fused2 keeps r6 pipeline: reg-prefetched drive, lambda^2-paired chain.
// Layouts:
//  Hbuf row (1024 u16): [re0,im0,re1,im1,...] (channel c at u16 2c/2c+1)
//  Bcat [1024][256]: row 2c -> Bre[c], row 2c+1 -> Bim[c]
//  Ccat [256][1280]: k=2c -> Cre[:,c], k=2c+1 -> -Cim[:,c]; k>=1024: D
//  P: [lam_re|lam_im|gamma|lamL_re|lamL_im|lam2_re|lam2_im] x512

#define TT     4096
#define BATCHN 16
#define MM     (BATCHN * TT)
#define LCH    64
#define NCH    (TT / LCH)   // 64

typedef unsigned short u16;
typedef unsigned int u32;
typedef short bf16x8 __attribute__((ext_vector_type(8)));
typedef float f32x4 __attribute__((ext_vector_type(4)));

__device__ __forceinline__ u16 f2bf(float f) {
  union { __hip_bfloat16 b; u16 u; } cv;
  cv.b = __float2bfloat16(f);
  return cv.u;
}
__device__ __forceinline__ float bf2f(u16 u) {
  union { u16 u; __hip_bfloat16 b; } cv;
  cv.u = u;
  return __bfloat162float(cv.b);
}

typedef __attribute__((address_space(3))) char lds_char;
typedef __attribute__((address_space(1))) const char gbl_char;
__device__ __forceinline__ void gload16(const void* g, void* l) {
  __builtin_amdgcn_global_load_lds((gbl_char*)g, (lds_char*)l, 16, 0, 0);
}

// ---------------- params ----------------
__global__ void k_params(const float* __restrict__ nu_log,
                         const float* __restrict__ theta_log,
                         float* __restrict__ P) {
  int h = threadIdx.x;
  if (h >= 512) return;
  double nu  = exp((double)nu_log[h]);
  double th  = exp((double)theta_log[h]);
  double mag = exp(-nu);
  double g   = sqrt(fmax(0.0, 1.0 - mag * mag));
  double magL = exp(-(double)LCH * nu);
  double aL   = (double)LCH * th;
  double mag2 = exp(-2.0 * nu);
  P[h]        = (float)(mag * cos(th));        // lam_re
  P[512 + h]  = (float)(mag * sin(th));        // lam_im
  P[1024 + h] = (float)g;                      // gamma
  P[1536 + h] = (float)(magL * cos(aL));       // lam^L re
  P[2048 + h] = (float)(magL * sin(aL));       // lam^L im
  P[2560 + h] = (float)(mag2 * cos(2.0 * th)); // lam^2 re
  P[3072 + h] = (float)(mag2 * sin(2.0 * th)); // lam^2 im
}

// ---------------- weight prep ----------------
__global__ void k_prep_w(const float* __restrict__ Bre, const float* __restrict__ Bim,
                         const float* __restrict__ Cre, const float* __restrict__ Cim,
                         const float* __restrict__ D, u16* __restrict__ Bcat,
                         u16* __restrict__ Ccat) {
  const int NB = 1024 * 256;
  const int NC = 256 * 1280;
  for (int idx = blockIdx.x * blockDim.x + threadIdx.x; idx < NB + NC;
       idx += gridDim.x * blockDim.x) {
    if (idx < NB) {
      int row = idx >> 8, col = idx & 255;
      int ch = row >> 1;
      float v = (row & 1) ? Bim[ch * 256 + col] : Bre[ch * 256 + col];
      Bcat[idx] = f2bf(v);
    } else {
      int j = idx - NB;
      int o = j / 1280, k = j % 1280;
      float v;
      if (k < 1024) {
        int ch = k >> 1;
        v = (k & 1) ? -Cim[o * 512 + ch] : Cre[o * 512 + ch];
      } else {
        v = D[o * 256 + (k - 1024)];
      }
      Ccat[j] = f2bf(v);
    }
  }
}

// ---------------- X -> bf16 ----------------
__global__ __launch_bounds__(256) void k_prep_x(const float* __restrict__ X,
                                                u16* __restrict__ Xb) {
  int idx = blockIdx.x * 256 + threadIdx.x;
  const float4* s = (const float4*)X + (size_t)idx * 2;
  float4 a = s[0], b = s[1];
  u16 o[8] = {f2bf(a.x), f2bf(a.y), f2bf(a.z), f2bf(a.w),
              f2bf(b.x), f2bf(b.y), f2bf(b.z), f2bf(b.w)};
  *(int4*)(Xb + (size_t)idx * 8) = *(const int4*)o;
}

// ------- GEMM1: Hbuf(drive, interleaved) = epi(Xb @ Bcat^T); fused finals ---
// 128x128 tile (rows = 128 t of one batch = 2 chunks; cols = 64 channels
// re/im-interleaved). Staging via global_load_lds (pre-swizzled source,
// linear LDS dest). Epilogue mirrors tile to LDS; 128 threads scan finals.
__global__ __launch_bounds__(256) void k_gemm1(
    const u16* __restrict__ Xb, const u16* __restrict__ Bcat,
    const float* __restrict__ P, const float* __restrict__ bhr,
    const float* __restrict__ bhi, u16* __restrict__ Hbuf,
    float* __restrict__ finr, float* __restrict__ fini) {
  __shared__ __align__(16) char smem[33280];  // staging 32KB | finals mirror
  char* sA = smem;
  char* sB = smem + 16384;
  u32* sF = (u32*)smem;                       // [128][65] u32, padded
  const int tid = threadIdx.x;
  const int lane = tid & 63;
  const int wid = tid >> 6;
  const int wr = wid >> 1, wc = wid & 1;
  const int mb = blockIdx.x * 128;
  const int nb = blockIdx.y * 128;

  f32x4 acc[4][4];
#pragma unroll
  for (int r = 0; r < 4; ++r)
#pragma unroll
    for (int c = 0; c < 4; ++c) acc[r][c] = (f32x4)0.f;

  for (int kt = 0; kt < 4; ++kt) {
    const int k0 = kt * 64;
    __syncthreads();
#pragma unroll
    for (int i = 0; i < 4; ++i) {
      int s = i * 256 + tid;
      int row = s >> 3, slot = s & 7;
      int swz = slot ^ (row & 7);
      gload16(Xb + (size_t)(mb + row) * 256 + k0 + swz * 8, sA + s * 16);
      gload16(Bcat + (size_t)(nb + row) * 256 + k0 + swz * 8, sB + s * 16);
    }
    __syncthreads();  // drains vmcnt (global_load_lds) + lgkm
#pragma unroll
    for (int kk = 0; kk < 2; ++kk) {
      bf16x8 af[4], bfr[4];
#pragma unroll
      for (int r = 0; r < 4; ++r) {
        int row = wr * 64 + r * 16 + (lane & 15);
        int slot = (kk * 4 + (lane >> 4)) ^ (row & 7);
        af[r] = *(const bf16x8*)(sA + row * 128 + slot * 16);
      }
#pragma unroll
      for (int c = 0; c < 4; ++c) {
        int row = wc * 64 + c * 16 + (lane & 15);
        int slot = (kk * 4 + (lane >> 4)) ^ (row & 7);
        bfr[c] = *(const bf16x8*)(sB + row * 128 + slot * 16);
      }
#pragma unroll
      for (int r = 0; r < 4; ++r)
#pragma unroll
        for (int c = 0; c < 4; ++c)
          acc[r][c] = __builtin_amdgcn_mfma_f32_16x16x32_bf16(af[r], bfr[c],
                                                              acc[r][c], 0, 0, 0);
    }
  }
  __syncthreads();  // staging reads done before sF overwrites smem

  const int rbase = (lane >> 4) * 4;
  const int cbase = lane & 15;
#pragma unroll
  for (int r = 0; r < 4; ++r)
#pragma unroll
    for (int c = 0; c < 4; ++c) {
      int col_l = wc * 64 + c * 16 + cbase;     // 0..127 interleaved
      int col = nb + col_l;                     // global Hbuf column
      int ch = col >> 1;                        // channel 0..511
      float g = P[1024 + ch];
      float bias = (col & 1) ? bhi[ch] : bhr[ch];
#pragma unroll
      for (int q = 0; q < 4; ++q) {
        int row_l = wr * 64 + r * 16 + rbase + q;
        int row = mb + row_l;
        u16 v = f2bf(fmaf(acc[r][c][q], g, bias));
        Hbuf[(size_t)row * 1024 + col] = v;
        // mirror into LDS for finals: u32 word (row_l, ch_l), half = col&1
        char* p = (char*)&sF[row_l * 65 + (col_l >> 1)];
        *(u16*)(p + (col_l & 1) * 2) = v;
      }
    }
  __syncthreads();

  // ---- fused chunk-final scan from LDS ----
  if (tid < 128) {
    int ch_l = tid & 63, half = tid >> 6;
    int ch = blockIdx.y * 64 + ch_l;
    float lr = P[ch], li = P[512 + ch];
    float hr = 0.f, hi = 0.f;
#pragma unroll 8
    for (int j = 0; j < LCH; ++j) {
      u32 pk = sF[(half * 64 + j) * 65 + ch_l];
      float dr = bf2f((u16)(pk & 0xffff));
      float di = bf2f((u16)(pk >> 16));
      float nr = fmaf(lr, hr, fmaf(-li, hi, dr));
      float ni = fmaf(lr, hi, fmaf(li, hr, di));
      hr = nr; hi = ni;
    }
    int b = mb >> 12;
    int chunk = ((mb & 4095) >> 6) + half;
    size_t f = ((size_t)b * NCH + chunk) * 512 + ch;
    finr[f] = hr; fini[f] = hi;
  }
}

// ---------------- carry chain ----------------
__global__ __launch_bounds__(512) void k_carry(
    const float* __restrict__ P, const float* __restrict__ finr,
    const float* __restrict__ fini, float* __restrict__ carr,
    float* __restrict__ cari) {
  const int h = threadIdx.x;
  const int b = blockIdx.x;
  const float Lr = P[1536 + h], Li = P[2048 + h];
  float cr = 0.f, ci = 0.f;
  for (int c = 0; c < NCH; ++c) {
    size_t idx = ((size_t)b * NCH + c) * 512 + h;
    carr[idx] = cr; cari[idx] = ci;
    float fr = finr[idx], fi = fini[idx];
    float nr = fmaf(Lr, cr, fmaf(-Li, ci, fr));
    float ni = fmaf(Lr, ci, fmaf(Li, cr, fi));
    cr = nr; ci = ni;
  }
}

// ---------------- fused scan + output GEMM ----------------
// One block per (chunk c=64 steps, batch b). 256 threads = 4 waves. M=64,
// N=256, K=1280. Per q-half: drive reg-prefetched (64 u32/thread),
// lambda^2-paired chain (serial depth 32), H -> LDS (swizzled), MFMA vs Ccat.
// q1 loads issued before MFMA-q0; X-tail loads issued before MFMA-q1.
#define CHAIN_PHASE(DBUF, CR, CI, LR, LI, LR2, LI2)                         \
  {                                                                         \
    float ur = (CR), ui = (CI);                                             \
    _Pragma("unroll") for (int k = 0; k < 32; ++k) {                        \
      u32 p0 = DBUF[2 * k], p1 = DBUF[2 * k + 1];                           \
      float der = bf2f((u16)(p0 & 0xffff)), dei = bf2f((u16)(p0 >> 16));    \
      float dor = bf2f((u16)(p1 & 0xffff)), doi = bf2f((u16)(p1 >> 16));    \
      float er = fmaf((LR), der, fmaf(-(LI), dei, dor));                    \
      float ei = fmaf((LR), dei, fmaf((LI), der, doi));                     \
      float h0r = fmaf((LR), ur, fmaf(-(LI), ui, der));                     \
      float h0i = fmaf((LR), ui, fmaf((LI), ur, dei));                      \
      float nur = fmaf((LR2), ur, fmaf(-(LI2), ui, er));                    \
      float nui = fmaf((LR2), ui, fmaf((LI2), ur, ei));                     \
      int j0 = 2 * k, j1 = 2 * k + 1;                                       \
      int s0 = ((tid >> 2) ^ (j0 & 7)) * 16 + (tid & 3) * 4;                \
      int s1 = ((tid >> 2) ^ (j1 & 7)) * 16 + (tid & 3) * 4;                \
      *(u32*)(Hs + j0 * 1024 + s0) = (u32)f2bf(h0r) | ((u32)f2bf(h0i) << 16); \
      *(u32*)(Hs + j1 * 1024 + s1) = (u32)f2bf(nur) | ((u32)f2bf(nui) << 16); \
      ur = nur; ui = nui;                                                   \
    }                                                                       \
  }

#define MFMA_PHASE(QOFF)                                                    \
  _Pragma("unroll 4") for (int ks = 0; ks < 16; ++ks) {                     \
    bf16x8 af[4], bfr[4];                                                   \
    _Pragma("unroll") for (int m = 0; m < 4; ++m) {                         \
      int row = m * 16 + (lane & 15);                                       \
      int slot = (ks * 4 + (lane >> 4)) ^ (row & 7);                        \
      af[m] = *(const bf16x8*)(Hs + row * 1024 + slot * 16);                \
    }                                                                       \
    _Pragma("unroll") for (int n = 0; n < 4; ++n) {                         \
      int col = w * 64 + n * 16 + (lane & 15);                              \
      bfr[n] = *(const bf16x8*)(Ccat + (size_t)col * 1280 + (QOFF) +        \
                                ks * 32 + (lane >> 4) * 8);                 \
    }                                                                       \
    _Pragma("unroll") for (int m = 0; m < 4; ++m)                           \
      _Pragma("unroll") for (int n = 0; n < 4; ++n)                         \
        acc[m][n] = __builtin_amdgcn_mfma_f32_16x16x32_bf16(af[m], bfr[n],  \
                                                            acc[m][n], 0, 0, 0); \
  }

__global__ __launch_bounds__(256, 2) void k_fused2(
    const float* __restrict__ P, const u16* __restrict__ Hbuf,
    const u16* __restrict__ Xb, const u16* __restrict__ Ccat,
    const float* __restrict__ carr, const float* __restrict__ cari,
    const float* __restrict__ bo, float* __restrict__ Y) {
  __shared__ __align__(16) char Hs[64 * 1024];  // 64 KiB
  const int tid = threadIdx.x;
  const int lane = tid & 63;
  const int w = tid >> 6;
  const int c = blockIdx.x;
  const int b = blockIdx.y;
  const int row0 = b * TT + c * LCH;

  f32x4 acc[4][4];
#pragma unroll
  for (int m = 0; m < 4; ++m)
#pragma unroll
    for (int n = 0; n < 4; ++n) acc[m][n] = (f32x4)0.f;

  const u32* H32 = (const u32*)Hbuf;
  const size_t cidx = ((size_t)b * NCH + c) * 512 + tid;
  const size_t base0 = (size_t)row0 * 512 + tid;

  // ---- q0: prefetch drive + carry, run chain into Hs ----
  u32 d0[64];
#pragma unroll
  for (int j = 0; j < 64; ++j) d0[j] = H32[base0 + (size_t)j * 512];
  float car0r = carr[cidx], car0i = cari[cidx];
  {
    const float lr = P[tid], li = P[512 + tid];
    const float lr2 = P[2560 + tid], li2 = P[3072 + tid];
    CHAIN_PHASE(d0, car0r, car0i, lr, li, lr2, li2)
  }

  // ---- q1 prefetch (lands under MFMA q0) ----
  u32 d1[64];
#pragma unroll
  for (int j = 0; j < 64; ++j) d1[j] = H32[base0 + 256 + (size_t)j * 512];
  float car1r = carr[cidx + 256], car1i = cari[cidx + 256];

  __syncthreads();
  MFMA_PHASE(0)
  __syncthreads();

  {
    const float lr = P[256 + tid], li = P[768 + tid];
    const float lr2 = P[2816 + tid], li2 = P[3328 + tid];
    CHAIN_PHASE(d1, car1r, car1i, lr, li, lr2, li2)
  }

  // ---- X-tail prefetch (lands under MFMA q1): 64 rows x 32 slots of 16B ----
  int4 xstg[8];
#pragma unroll
  for (int i = 0; i < 8; ++i) {
    int p = i * 256 + tid;               // 0..2047
    int row = p >> 5, slot = p & 31;
    xstg[i] = *(const int4*)(Xb + (size_t)(row0 + row) * 256 +
                             ((slot ^ (row & 7)) * 8));
  }

  __syncthreads();
  MFMA_PHASE(512)
  __syncthreads();

  // ---- X tail: write staged Xb [64][512B], MFMA vs D columns ----
#pragma unroll
  for (int i = 0; i < 8; ++i) {
    int p = i * 256 + tid;
    int row = p >> 5, slot = p & 31;
    *(int4*)(Hs + row * 512 + slot * 16) = xstg[i];
  }
  __syncthreads();
#pragma unroll 2
  for (int ks = 0; ks < 8; ++ks) {
    bf16x8 af[4], bfr[4];
#pragma unroll
    for (int m = 0; m < 4; ++m) {
      int row = m * 16 + (lane & 15);
      int slot = (ks * 4 + (lane >> 4)) ^ (row & 7);
      af[m] = *(const bf16x8*)(Hs + row * 512 + slot * 16);
    }
#pragma unroll
    for (int n = 0; n < 4; ++n) {
      int col = w * 64 + n * 16 + (lane & 15);
      bfr[n] = *(const bf16x8*)(Ccat + (size_t)col * 1280 + 1024 +
                                ks * 32 + (lane >> 4) * 8);
    }
#pragma unroll
    for (int m = 0; m < 4; ++m)
#pragma unroll
      for (int n = 0; n < 4; ++n)
        acc[m][n] = __builtin_amdgcn_mfma_f32_16x16x32_bf16(af[m], bfr[n],
                                                            acc[m][n], 0, 0, 0);
  }

  // ---- epilogue ----
  const int rb = (lane >> 4) * 4;
  const int cb = lane & 15;
#pragma unroll
  for (int m = 0; m < 4; ++m)
#pragma unroll
    for (int n = 0; n < 4; ++n) {
      int col = w * 64 + n * 16 + cb;
      float bias = bo[col];
#pragma unroll
      for (int qq = 0; qq < 4; ++qq) {
        int row = row0 + m * 16 + rb + qq;
        Y[(size_t)row * 256 + col] = acc[m][n][qq] + bias;
      }
    }
}

extern "C" void kernel_launch(void* const* d_in, const int* in_sizes, int n_in,
                              void* d_out, int out_size, void* d_ws, size_t ws_size,
                              hipStream_t stream) {
  const float* X        = (const float*)d_in[0];
  const float* nu_log   = (const float*)d_in[1];
  const float* theta_lg = (const float*)d_in[2];
  const float* Bre      = (const float*)d_in[3];
  const float* Bim      = (const float*)d_in[4];
  const float* Cre      = (const float*)d_in[5];
  const float* Cim      = (const float*)d_in[6];
  const float* D        = (const float*)d_in[7];
  const float* bhr      = (const float*)d_in[8];
  const float* bhi      = (const float*)d_in[9];
  const float* bo       = (const float*)d_in[10];
  float* Y = (float*)d_out;
  char* ws = (char*)d_ws;

  size_t off = 0;
  float* P = (float*)(ws + off);            off += 4096 * 4;
  off = (off + 255) & ~(size_t)255;
  u16* Hbuf = (u16*)(ws + off);             off += (size_t)MM * 1024 * 2;  // 128 MiB
  u16* Xb   = (u16*)(ws + off);             off += (size_t)MM * 256 * 2;   // 32 MiB
  u16* Bcat = (u16*)(ws + off);             off += 1024 * 256 * 2;
  u16* Ccat = (u16*)(ws + off);             off += 256 * 1280 * 2;
  float* finr = (float*)(ws + off);         off += (size_t)BATCHN * NCH * 512 * 4;
  float* fini = (float*)(ws + off);         off += (size_t)BATCHN * NCH * 512 * 4;
  float* carr = (float*)(ws + off);         off += (size_t)BATCHN * NCH * 512 * 4;
  float* cari = (float*)(ws + off);         off += (size_t)BATCHN * NCH * 512 * 4;
  if (ws_size < off) return;

  k_params<<<1, 512, 0, stream>>>(nu_log, theta_lg, P);
  k_prep_w<<<512, 256, 0, stream>>>(Bre, Bim, Cre, Cim, D, Bcat, Ccat);
  k_prep_x<<<MM * 256 / (256 * 8), 256, 0, stream>>>(X, Xb);
  k_gemm1<<<dim3(MM / 128, 8), 256, 0, stream>>>(Xb, Bcat, P, bhr, bhi, Hbuf,
                                                 finr, fini);
  k_carry<<<BATCHN, 512, 0, stream>>>(P, finr, fini, carr, cari);
  k_fused2<<<dim3(NCH, BATCHN), 256, 0, stream>>>(P, Hbuf, Xb, Ccat, carr, cari,
                                                  bo, Y);
}